// Round 2
// baseline (151.042 us; speedup 1.0000x reference)
//
#include <hip/hip_runtime.h>

// Conv2D 15x15 valid, 4096^2 fp32 -> 4082^2 fp32, via bf16 MFMA Toeplitz-band.
//
// R2: 32x32x16 MFMA (was 16x16x32). A(32x16) feeds 32x32 outputs -> LDS
// A-traffic 3 B/output/kh (was 4), conflicts -25%. Per kh, 3 k-tiles cover
// x-cols [0,48) for 32 output cols: C += A_s(32x16) * B_s(16x32),
// B_s[k][n] = w[kh][16s+k-n] (0 outside band). B table = 45 KB in d_ws,
// streamed per kh via global_load_dwordx4 (all waves in phase -> L1/L2 hot).
//
// Block: 512 thr = 8 waves, 64x128 output tile (wave = one 32x32 tile).
// __launch_bounds__(512,8) -> 4 blocks/CU = 32 waves = 100% occupancy.
// LDS: x-tile 142x80 bf16, stride 88 (176 B rows). Edge blocks (bx==63 or
// by==31) take the clamped path; clamped data only feeds masked outputs.

#define HIN 4096
#define WIN 4096
#define KH 15
#define KW 15
#define OH (HIN - KH + 1)  // 4082
#define OW (WIN - KW + 1)  // 4082

#define BX 64
#define BY 128
#define XROWS (BY + KH - 1)     // 142 staged input rows
#define XCOLS 80                // staged input cols (64 + 14, padded to 80)
#define LDSW 88                 // bf16 row stride (176 B -> bank skew 12 dwords)
#define NSH (XROWS * LDSW)      // 12496 shorts = 24992 B LDS
#define NB4 (XCOLS / 4)         // 20 float4 per staged row
#define NITEM (XROWS * NB4)     // 2840 staging items per block
#define NTHR 512

typedef short bf16x8  __attribute__((ext_vector_type(8)));
typedef float f32x16  __attribute__((ext_vector_type(16)));

static __device__ inline short f2bf(float f) {  // fp32 -> bf16 RNE
    unsigned u = __float_as_uint(f);
    u += 0x7fffu + ((u >> 16) & 1u);
    return (short)(u >> 16);
}

// ---- prep: build B-fragment table (15 kh x 3 ktiles x 64 lanes x bf16x8) ----
// 32x32x16 B-operand layout: lane L holds B[k=(L>>5)*8+j][n=L&31], j=0..7,
// with B_s[k][n] = w[kh][16s + k - n] (0 outside [0,15)).
__global__ void conv2d_btab(const float* __restrict__ w, short* __restrict__ btab) {
    const int e = blockIdx.x * 256 + threadIdx.x;
    if (e >= KH * 3 * 64) return;
    const int kh = e / (3 * 64);
    const int s  = (e >> 6) % 3;
    const int L  = e & 63;
    const int n  = L & 31;
    const int h  = L >> 5;
    bf16x8 bv;
#pragma unroll
    for (int j = 0; j < 8; ++j) {
        const int d = 16 * s + h * 8 + j - n;          // x-col - n
        bv[j] = (d >= 0 && d < KW) ? f2bf(w[kh * KW + d]) : (short)0;
    }
    *reinterpret_cast<bf16x8*>(&btab[(size_t)e * 8]) = bv;
}

__global__ __launch_bounds__(NTHR, 8)
void conv2d_mfma(const float* __restrict__ x,
                 const short* __restrict__ btab,
                 const float* __restrict__ bias,
                 float* __restrict__ out) {
    __shared__ short lds[NSH];

    const int tid = threadIdx.x;
    const int ox0 = blockIdx.x * BX;
    const int oy0 = blockIdx.y * BY;

    // ---------------- stage x tile: 142 x 80 fp32 -> bf16 LDS ----------------
    if (ox0 + XCOLS <= WIN && oy0 + XROWS <= HIN) {
        // interior fast path: no clamps; batch-issue all loads, then convert
        float4 v[6];
#pragma unroll
        for (int i = 0; i < 6; ++i) {
            const int f = tid + NTHR * i;
            if (f < NITEM) {
                const int r  = f / NB4;
                const int c4 = (f - r * NB4) * 4;
                v[i] = *reinterpret_cast<const float4*>(&x[(size_t)(oy0 + r) * WIN + ox0 + c4]);
            }
        }
#pragma unroll
        for (int i = 0; i < 6; ++i) {
            const int f = tid + NTHR * i;
            if (f < NITEM) {
                const int r  = f / NB4;
                const int c4 = (f - r * NB4) * 4;
                short4 s;
                s.x = f2bf(v[i].x); s.y = f2bf(v[i].y);
                s.z = f2bf(v[i].z); s.w = f2bf(v[i].w);
                *reinterpret_cast<short4*>(&lds[r * LDSW + c4]) = s;   // ds_write_b64
            }
        }
    } else {
        // edge blocks (bx==63 or by==31): clamped per-item path
        for (int f = tid; f < NITEM; f += NTHR) {
            const int r  = f / NB4;
            const int c4 = (f - r * NB4) * 4;
            int gy = oy0 + r;
            if (gy > HIN - 1) gy = HIN - 1;   // clamped rows feed only masked outputs
            const int gx = ox0 + c4;
            float4 v;
            if (gx + 3 <= WIN - 1) {
                v = *reinterpret_cast<const float4*>(&x[(size_t)gy * WIN + gx]);
            } else {
                const float* row = &x[(size_t)gy * WIN];
                const int x0 = (gx + 0 > WIN - 1) ? WIN - 1 : gx + 0;
                const int x1 = (gx + 1 > WIN - 1) ? WIN - 1 : gx + 1;
                const int x2 = (gx + 2 > WIN - 1) ? WIN - 1 : gx + 2;
                const int x3 = (gx + 3 > WIN - 1) ? WIN - 1 : gx + 3;
                v = make_float4(row[x0], row[x1], row[x2], row[x3]);
            }
            short4 s;
            s.x = f2bf(v.x); s.y = f2bf(v.y); s.z = f2bf(v.z); s.w = f2bf(v.w);
            *reinterpret_cast<short4*>(&lds[r * LDSW + c4]) = s;
        }
    }
    __syncthreads();

    // ------------- compute: 15 kh x 3 ktiles of 32x32x16 MFMA per wave -------------
    const int lane  = tid & 63;
    const int wv    = tid >> 6;          // wave 0..7
    const int ctile = (wv & 1) * 32;     // wave's output-col tile within block
    const int rtile = (wv >> 1) * 32;    // wave's output-row tile within block
    const int m     = lane & 31;         // A row / D col index
    const int h     = lane >> 5;         // k-half

    f32x16 acc = (f32x16){0.f};

    // A-frag: row rtile+m+kh, cols ctile + 16s + 8h .. +8  (imm-friendly offsets)
    const short*  abase = &lds[(rtile + m) * LDSW + ctile + h * 8];
    const bf16x8* bt    = reinterpret_cast<const bf16x8*>(btab) + lane;
#pragma unroll
    for (int kh = 0; kh < KH; ++kh) {
#pragma unroll
        for (int s = 0; s < 3; ++s) {
            const bf16x8 b = bt[(kh * 3 + s) * 64];      // global dwordx4, L1/L2-hot
            const bf16x8 a =
                *reinterpret_cast<const bf16x8*>(abase + kh * LDSW + s * 16);  // ds_read_b128
            acc = __builtin_amdgcn_mfma_f32_32x32x16_bf16(a, b, acc, 0, 0, 0);
        }
    }

    // ---- epilogue: D layout col=lane&31, row=(reg&3)+8*(reg>>2)+4*(lane>>5) ----
    const float b0  = bias[0];
    const int   col = ox0 + ctile + m;
    const int   rw0 = oy0 + rtile + 4 * h;
    if (col < OW) {
#pragma unroll
        for (int reg = 0; reg < 16; ++reg) {
            const int row = rw0 + (reg & 3) + 8 * (reg >> 2);
            if (row < OH)
                out[(size_t)row * OW + col] = acc[reg] + b0;
        }
    }
}

extern "C" void kernel_launch(void* const* d_in, const int* in_sizes, int n_in,
                              void* d_out, int out_size, void* d_ws, size_t ws_size,
                              hipStream_t stream) {
    const float* x    = (const float*)d_in[0];
    const float* w    = (const float*)d_in[1];
    const float* bias = (const float*)d_in[2];
    float* out        = (float*)d_out;
    short* btab       = (short*)d_ws;   // 15*3*64*8 shorts = 46080 B

    conv2d_btab<<<dim3((KH * 3 * 64 + 255) / 256), dim3(256), 0, stream>>>(w, btab);

    dim3 grid((OW + BX - 1) / BX, (OH + BY - 1) / BY);  // 64 x 32
    dim3 block(NTHR);
    conv2d_mfma<<<grid, block, 0, stream>>>(x, btab, bias, out);
}